// Round 8
// baseline (445.236 us; speedup 1.0000x reference)
//
#include <hip/hip_runtime.h>

#define DIN   128
#define DHID  16
#define NCLS  40
#define RSH_C 9            // coarse bucket = 512 rows
#define RROWS_C 512
#define BATCH 8192         // edges per k_bucket2 block

__device__ __forceinline__ unsigned short f2bf(float f) {
    unsigned u = __float_as_uint(f);
    unsigned r = (u + 0x7FFFu + ((u >> 16) & 1u)) >> 16;   // RNE
    return (unsigned short)r;
}

// ------------- K1: X1 = H @ W1 -> two bf16 half-tables (n x 8) -------------
__global__ __launch_bounds__(256) void k1_gemm_hw1_split(
    const float* __restrict__ H, const float* __restrict__ W1,
    unsigned short* __restrict__ X1a, unsigned short* __restrict__ X1c, int n)
{
    __shared__ __align__(16) float w[DIN * DHID];
    for (int i = threadIdx.x; i < DIN * DHID; i += 256) w[i] = W1[i];
    __syncthreads();
    int r = blockIdx.x * 256 + threadIdx.x;
    if (r >= n) return;
    const float4* hrow = (const float4*)(H + (size_t)r * DIN);
    float acc[DHID];
#pragma unroll
    for (int j = 0; j < DHID; ++j) acc[j] = 0.f;
#pragma unroll 4
    for (int k4 = 0; k4 < DIN / 4; ++k4) {
        float4 h = hrow[k4];
        float hh[4] = {h.x, h.y, h.z, h.w};
#pragma unroll
        for (int kk = 0; kk < 4; ++kk) {
#pragma unroll
            for (int j4 = 0; j4 < DHID / 4; ++j4) {
                float4 wv = *(const float4*)&w[(4 * k4 + kk) * DHID + 4 * j4];
                acc[4 * j4 + 0] += hh[kk] * wv.x;
                acc[4 * j4 + 1] += hh[kk] * wv.y;
                acc[4 * j4 + 2] += hh[kk] * wv.z;
                acc[4 * j4 + 3] += hh[kk] * wv.w;
            }
        }
    }
    unsigned pk[8];
#pragma unroll
    for (int q = 0; q < 8; ++q)
        pk[q] = (unsigned)f2bf(acc[2 * q]) | ((unsigned)f2bf(acc[2 * q + 1]) << 16);
    *(uint4*)(X1a + (size_t)r * 8) = make_uint4(pk[0], pk[1], pk[2], pk[3]);
    *(uint4*)(X1c + (size_t)r * 8) = make_uint4(pk[4], pk[5], pk[6], pk[7]);
}

// ---------------- coarse histogram (4-way dup LDS counters) ----------------
__global__ __launch_bounds__(256) void k_hist_b(
    const int* __restrict__ rows, unsigned* __restrict__ gcnt, int nnz, int nb)
{
    __shared__ unsigned c4[4][RROWS_C];
    int tid = threadIdx.x;
    for (int i = tid; i < 4 * RROWS_C; i += 256) ((unsigned*)c4)[i] = 0;
    __syncthreads();
    int cp = (tid >> 6) & 3;
    for (int e = blockIdx.x * 256 + tid; e < nnz; e += gridDim.x * 256)
        atomicAdd(&c4[cp][((unsigned)rows[e]) >> RSH_C], 1u);
    __syncthreads();
    for (int b = tid; b < nb; b += 256) {
        unsigned s = c4[0][b] + c4[1][b] + c4[2][b] + c4[3][b];
        if (s) atomicAdd(&gcnt[b], s);
    }
}

// ---------------- single-block scan over nb (<=512) buckets ----------------
__global__ __launch_bounds__(512) void k_scan_all(
    const unsigned* __restrict__ cnt, unsigned* __restrict__ rs_b,
    unsigned* __restrict__ cur_b, int nb, unsigned nnz)
{
    __shared__ unsigned s[512];
    int tid = threadIdx.x;
    unsigned v = (tid < nb) ? cnt[tid] : 0u;
    s[tid] = v; __syncthreads();
    for (int off = 1; off < 512; off <<= 1) {
        unsigned t = (tid >= off) ? s[tid - off] : 0u;
        __syncthreads();
        s[tid] += t;
        __syncthreads();
    }
    if (tid < nb) {
        unsigned e = s[tid] - v;
        rs_b[tid] = e;
        cur_b[tid] = e;
    }
    if (tid == 0) rs_b[nb] = nnz;
}

// ------- bucket placement v2: LDS multi-split, coalesced flush -------------
__global__ __launch_bounds__(512) void k_bucket2(
    const int* __restrict__ rows, const int* __restrict__ cols,
    const float* __restrict__ vals, unsigned* __restrict__ gcur,
    int2* __restrict__ colvB, int nnz, int nb)
{
    __shared__ int2 st[BATCH];                 // 64 KB bucket-sorted staging
    __shared__ unsigned short bb[BATCH];       // 16 KB bucket id per slot
    __shared__ unsigned h4[4][512];            // 8 KB 4-dup histogram
    __shared__ unsigned scn[512];
    __shared__ unsigned sstart[512];
    __shared__ unsigned pos[512];
    __shared__ unsigned gbase[512];
    int tid = threadIdx.x;
    int e0 = blockIdx.x * BATCH;
    int m = nnz - e0; if (m > BATCH) m = BATCH;

    int r_[BATCH / 512]; int c_[BATCH / 512]; float v_[BATCH / 512];
#pragma unroll
    for (int q = 0; q < BATCH / 512; ++q) {
        int i = q * 512 + tid;
        if (i < m) { r_[q] = rows[e0 + i]; c_[q] = cols[e0 + i]; v_[q] = vals[e0 + i]; }
    }
    for (int i = tid; i < 4 * 512; i += 512) ((unsigned*)h4)[i] = 0;
    __syncthreads();
    int cp = (tid >> 7) & 3;
#pragma unroll
    for (int q = 0; q < BATCH / 512; ++q)
        if (q * 512 + tid < m) atomicAdd(&h4[cp][((unsigned)r_[q]) >> RSH_C], 1u);
    __syncthreads();
    scn[tid] = h4[0][tid] + h4[1][tid] + h4[2][tid] + h4[3][tid];
    __syncthreads();
    for (int off = 1; off < 512; off <<= 1) {
        unsigned t = (tid >= off) ? scn[tid - off] : 0u;
        __syncthreads();
        scn[tid] += t;
        __syncthreads();
    }
    unsigned vcnt = scn[tid] - (tid ? scn[tid - 1] : 0u);
    unsigned excl = scn[tid] - vcnt;
    sstart[tid] = excl;
    pos[tid] = excl;
    gbase[tid] = (tid < nb && vcnt) ? atomicAdd(&gcur[tid], vcnt) : 0u;
    __syncthreads();
#pragma unroll
    for (int q = 0; q < BATCH / 512; ++q) {
        if (q * 512 + tid < m) {
            int b = ((unsigned)r_[q]) >> RSH_C;
            unsigned p = atomicAdd(&pos[b], 1u);
            st[p] = make_int2(c_[q] | ((r_[q] & (RROWS_C - 1)) << 18),
                              __float_as_int(v_[q]));
            bb[p] = (unsigned short)b;
        }
    }
    __syncthreads();
    for (int i = tid; i < m; i += 512) {
        int b = bb[i];
        colvB[gbase[b] + (i - sstart[b])] = st[i];
    }
}

// -------- per-coarse-bucket sort -> per-row CSR, compressed 4B records -----
__global__ __launch_bounds__(512) void k_sortb(
    const unsigned* __restrict__ rs_b, const int2* __restrict__ colvB,
    unsigned* __restrict__ colv2, unsigned* __restrict__ rs_row,
    int n, int nb, unsigned nnz)
{
    __shared__ unsigned c4[4][RROWS_C];
    __shared__ unsigned scn[RROWS_C];
    __shared__ unsigned pos[RROWS_C];
    int b = blockIdx.x, tid = threadIdx.x;
    unsigned s0 = rs_b[b], s1 = rs_b[b + 1];
    int m = (int)(s1 - s0);
    for (int i = tid; i < 4 * RROWS_C; i += 512) ((unsigned*)c4)[i] = 0;
    __syncthreads();
    int cp = (tid >> 7) & 3;
    for (int i = tid; i < m; i += 512)
        atomicAdd(&c4[cp][((unsigned)colvB[s0 + i].x) >> 18], 1u);
    __syncthreads();
    scn[tid] = c4[0][tid] + c4[1][tid] + c4[2][tid] + c4[3][tid];
    __syncthreads();
    for (int off = 1; off < RROWS_C; off <<= 1) {
        unsigned t = (tid >= off) ? scn[tid - off] : 0u;
        __syncthreads();
        scn[tid] += t;
        __syncthreads();
    }
    unsigned excl = tid ? scn[tid - 1] : 0u;
    pos[tid] = excl;
    int row = b * RROWS_C + tid;
    if (row < n) rs_row[row] = s0 + excl;
    if (b == nb - 1 && tid == 0) rs_row[n] = nnz;
    __syncthreads();
    for (int i = tid; i < m; i += 512) {
        int2 e = colvB[s0 + i];
        int lr = ((unsigned)e.x) >> 18;
        unsigned p = atomicAdd(&pos[lr], 1u);
        float v = __int_as_float(e.y);
        unsigned q = (unsigned)(v * 16383.f + 0.5f);
        if (q > 16383u) q = 16383u;
        colv2[s0 + p] = ((unsigned)e.x & 0x3FFFFu) | (q << 18);
    }
}

// ---- SpMM over an 8-feature half-table (3.2 MB -> L2-resident) -----------
// wave = 32 edge-groups x 2 lanes; lane l loads 4 bf16 (8B) of the row.
// RELU=1: dst = bf16 relu(sum + bias[l*4..]), else raw sums.
template<int RELU>
__global__ __launch_bounds__(256) void k_spmm8(
    const unsigned* __restrict__ rs, const unsigned* __restrict__ colv2,
    const unsigned short* __restrict__ srcb,   // n x 8 bf16
    const float* __restrict__ bias,            // 8 floats for this half
    unsigned short* __restrict__ dstb, int n)  // n x 8 bf16
{
    const float DQ = 1.f / 16383.f;
    int w = blockIdx.x * 4 + (threadIdx.x >> 6);
    if (w >= n) return;
    int lane = threadIdx.x & 63;
    int g = lane >> 1, l = lane & 1;
    unsigned s0 = rs[w], s1 = rs[w + 1];
    float acc0 = 0.f, acc1 = 0.f, acc2 = 0.f, acc3 = 0.f;
    for (unsigned i = s0 + g; i < s1; i += 32) {
        unsigned rec = colv2[i];
        float vv = (float)(rec >> 18) * DQ;
        uint2 d = *((const uint2*)(srcb + (size_t)(rec & 0x3FFFFu) * 8) + l);
        acc0 += __uint_as_float(d.x << 16) * vv;
        acc1 += __uint_as_float(d.x & 0xFFFF0000u) * vv;
        acc2 += __uint_as_float(d.y << 16) * vv;
        acc3 += __uint_as_float(d.y & 0xFFFF0000u) * vv;
    }
    // reduce across the 32 edge-groups (keep l bit)
#pragma unroll
    for (int off = 2; off < 64; off <<= 1) {
        acc0 += __shfl_xor(acc0, off, 64);
        acc1 += __shfl_xor(acc1, off, 64);
        acc2 += __shfl_xor(acc2, off, 64);
        acc3 += __shfl_xor(acc3, off, 64);
    }
    if (lane < 2) {
        float4 bv = ((const float4*)bias)[l];
        float a0, a1, a2, a3;
        if (RELU) {
            a0 = fmaxf(acc0 + bv.x, 0.f);
            a1 = fmaxf(acc1 + bv.y, 0.f);
            a2 = fmaxf(acc2 + bv.z, 0.f);
            a3 = fmaxf(acc3 + bv.w, 0.f);
        } else {
            a0 = acc0; a1 = acc1; a2 = acc2; a3 = acc3;
        }
        uint2 pk;
        pk.x = (unsigned)f2bf(a0) | ((unsigned)f2bf(a1) << 16);
        pk.y = (unsigned)f2bf(a2) | ((unsigned)f2bf(a3) << 16);
        *((uint2*)(dstb + (size_t)w * 8) + l) = pk;
    }
}

// ----- K4: out = log_softmax(relu([Ta|Tc] @ W2 + b2)), thread per row ------
__global__ __launch_bounds__(256) void k4_final_split(
    const unsigned short* __restrict__ Ta, const unsigned short* __restrict__ Tc,
    const float* __restrict__ W2, const float* __restrict__ b2,
    float* __restrict__ out, int n)
{
    __shared__ __align__(16) float w[DHID * NCLS];
    __shared__ float bb[NCLS];
    for (int i = threadIdx.x; i < DHID * NCLS; i += 256) w[i] = W2[i];
    if (threadIdx.x < NCLS) bb[threadIdx.x] = b2[threadIdx.x];
    __syncthreads();
    int r = blockIdx.x * 256 + threadIdx.x;
    if (r >= n) return;
    uint4 pa = *(const uint4*)(Ta + (size_t)r * 8);
    uint4 pc = *(const uint4*)(Tc + (size_t)r * 8);
    unsigned u[8] = {pa.x, pa.y, pa.z, pa.w, pc.x, pc.y, pc.z, pc.w};
    float t[DHID];
#pragma unroll
    for (int q = 0; q < 8; ++q) {
        t[2 * q]     = __uint_as_float(u[q] << 16);
        t[2 * q + 1] = __uint_as_float(u[q] & 0xFFFF0000u);
    }
    float o[NCLS];
#pragma unroll
    for (int j = 0; j < NCLS; ++j) o[j] = bb[j];
#pragma unroll 4
    for (int k = 0; k < DHID; ++k) {
        float tk = t[k];
#pragma unroll
        for (int j4 = 0; j4 < NCLS / 4; ++j4) {
            float4 wv = *(const float4*)&w[k * NCLS + 4 * j4];
            o[4*j4+0] += tk * wv.x;
            o[4*j4+1] += tk * wv.y;
            o[4*j4+2] += tk * wv.z;
            o[4*j4+3] += tk * wv.w;
        }
    }
    float mx = 0.f;
#pragma unroll
    for (int j = 0; j < NCLS; ++j) {
        o[j] = fmaxf(o[j], 0.f);
        mx = fmaxf(mx, o[j]);
    }
    float s = 0.f;
#pragma unroll
    for (int j = 0; j < NCLS; ++j) s += __expf(o[j] - mx);
    float ls = mx + __logf(s);
    float4* orow = (float4*)(out + (size_t)r * NCLS);
#pragma unroll
    for (int j4 = 0; j4 < NCLS / 4; ++j4)
        orow[j4] = make_float4(o[4*j4+0]-ls, o[4*j4+1]-ls, o[4*j4+2]-ls, o[4*j4+3]-ls);
}

// ---------------- fallback (round-1 scatter path, fp32) ----------------
__global__ __launch_bounds__(256) void k1_gemm_hw1_f32(
    const float* __restrict__ H, const float* __restrict__ W1,
    float* __restrict__ X1, int n)
{
    __shared__ __align__(16) float w[DIN * DHID];
    for (int i = threadIdx.x; i < DIN * DHID; i += 256) w[i] = W1[i];
    __syncthreads();
    int r = blockIdx.x * 256 + threadIdx.x;
    if (r >= n) return;
    const float4* hrow = (const float4*)(H + (size_t)r * DIN);
    float acc[DHID];
#pragma unroll
    for (int j = 0; j < DHID; ++j) acc[j] = 0.f;
    for (int k4 = 0; k4 < DIN / 4; ++k4) {
        float4 h = hrow[k4];
        float hh[4] = {h.x, h.y, h.z, h.w};
#pragma unroll
        for (int kk = 0; kk < 4; ++kk)
#pragma unroll
            for (int j = 0; j < DHID; ++j)
                acc[j] += hh[kk] * w[(4 * k4 + kk) * DHID + j];
    }
    float4* o = (float4*)(X1 + (size_t)r * DHID);
#pragma unroll
    for (int q = 0; q < DHID / 4; ++q)
        o[q] = make_float4(acc[4*q], acc[4*q+1], acc[4*q+2], acc[4*q+3]);
}

__global__ __launch_bounds__(256) void k2_scatter16(
    const int* __restrict__ rows, const int* __restrict__ cols,
    const float* __restrict__ vals, const float* __restrict__ src,
    const float* __restrict__ bias, int do_relu,
    float* __restrict__ dst, int nnz)
{
    unsigned int tid = blockIdx.x * 256u + threadIdx.x;
    int e = (int)(tid >> 4);
    int j = (int)(tid & 15u);
    if (e >= nnz) return;
    int c = cols[e];
    int r = rows[e];
    float x = src[(size_t)c * DHID + j];
    if (do_relu) x = fmaxf(x + bias[j], 0.f);
    atomicAdd(&dst[(size_t)r * DHID + j], x * vals[e]);
}

__global__ __launch_bounds__(256) void k4_final_f32(
    const float* __restrict__ T, const float* __restrict__ W2,
    const float* __restrict__ b2, float* __restrict__ out, int n)
{
    __shared__ __align__(16) float w[DHID * NCLS];
    __shared__ float bb[NCLS];
    for (int i = threadIdx.x; i < DHID * NCLS; i += 256) w[i] = W2[i];
    if (threadIdx.x < NCLS) bb[threadIdx.x] = b2[threadIdx.x];
    __syncthreads();
    int r = blockIdx.x * 256 + threadIdx.x;
    if (r >= n) return;
    float t[DHID];
    const float4* trow = (const float4*)(T + (size_t)r * DHID);
#pragma unroll
    for (int q = 0; q < DHID / 4; ++q) {
        float4 v = trow[q];
        t[4*q+0] = v.x; t[4*q+1] = v.y; t[4*q+2] = v.z; t[4*q+3] = v.w;
    }
    float o[NCLS];
#pragma unroll
    for (int j = 0; j < NCLS; ++j) o[j] = bb[j];
    for (int k = 0; k < DHID; ++k) {
        float tk = t[k];
#pragma unroll
        for (int j = 0; j < NCLS; ++j) o[j] += tk * w[k * NCLS + j];
    }
    float mx = 0.f;
#pragma unroll
    for (int j = 0; j < NCLS; ++j) { o[j] = fmaxf(o[j], 0.f); mx = fmaxf(mx, o[j]); }
    float s = 0.f;
#pragma unroll
    for (int j = 0; j < NCLS; ++j) s += __expf(o[j] - mx);
    float ls = mx + __logf(s);
#pragma unroll
    for (int j = 0; j < NCLS; ++j) out[(size_t)r * NCLS + j] = o[j] - ls;
}

extern "C" void kernel_launch(void* const* d_in, const int* in_sizes, int n_in,
                              void* d_out, int out_size, void* d_ws, size_t ws_size,
                              hipStream_t stream)
{
    const float* H    = (const float*)d_in[0];
    const int*   rows = (const int*)d_in[1];
    const int*   cols = (const int*)d_in[2];
    const float* vals = (const float*)d_in[3];
    const float* W1   = (const float*)d_in[4];
    const float* b1   = (const float*)d_in[5];
    const float* W2   = (const float*)d_in[6];
    const float* b2   = (const float*)d_in[7];
    float* out = (float*)d_out;

    int n   = in_sizes[0] / DIN;              // 200000
    int nnz = in_sizes[1];                    // 6,400,000
    int nb  = (n + RROWS_C - 1) >> RSH_C;     // 391 coarse buckets

    // ---- workspace layout (~77.6 MB) ----
    unsigned* rs_b   = (unsigned*)d_ws;               // nb+1
    unsigned* cur_b  = rs_b + (nb + 1);               // nb
    unsigned* cnt_b  = cur_b + nb;                    // nb
    unsigned* rs_row = cnt_b + nb;                    // n+1
    size_t off = (size_t)((char*)(rs_row + n + 1) - (char*)d_ws);
    off = (off + 63) & ~(size_t)63;
    unsigned* colv2 = (unsigned*)((char*)d_ws + off); // nnz u32 (compressed CSR)
    off += (size_t)nnz * sizeof(unsigned);
    off = (off + 63) & ~(size_t)63;
    int2* colvB = (int2*)((char*)d_ws + off);         // nnz int2 (bucket stage)
    size_t needed = off + (size_t)nnz * sizeof(int2);
    // feature-split bf16 half-tables overlay colvB (dead after k_sortb):
    unsigned short* X1a = (unsigned short*)colvB;     // n*8 bf16 (f0..7)
    unsigned short* X1c = X1a + (size_t)n * 8;        // n*8 bf16 (f8..15)
    unsigned short* H1a = X1c + (size_t)n * 8;
    unsigned short* H1c = H1a + (size_t)n * 8;
    unsigned short* Ta  = H1c + (size_t)n * 8;
    unsigned short* Tc  = Ta  + (size_t)n * 8;        // total 19.2 MB < 51.2 MB

    int rb  = (n + 255) / 256;
    int sb4 = (n + 3) / 4;

    if (nb <= RROWS_C && n <= (1 << 18) && needed <= ws_size) {
        hipMemsetAsync(cnt_b, 0, (size_t)nb * sizeof(unsigned), stream);
        k_hist_b<<<1024, 256, 0, stream>>>(rows, cnt_b, nnz, nb);
        k_scan_all<<<1, 512, 0, stream>>>(cnt_b, rs_b, cur_b, nb, (unsigned)nnz);
        int nbk = (nnz + BATCH - 1) / BATCH;
        k_bucket2<<<nbk, 512, 0, stream>>>(rows, cols, vals, cur_b, colvB, nnz, nb);
        k_sortb<<<nb, 512, 0, stream>>>(rs_b, colvB, colv2, rs_row, n, nb, (unsigned)nnz);
        // X1 = H @ W1 -> split tables (overlays dead colvB region)
        k1_gemm_hw1_split<<<rb, 256, 0, stream>>>(H, W1, X1a, X1c, n);
        // H1 = relu(A @ X1 + b1), feature halves (each table 3.2 MB, L2-resident)
        k_spmm8<1><<<sb4, 256, 0, stream>>>(rs_row, colv2, X1a, b1,     H1a, n);
        k_spmm8<1><<<sb4, 256, 0, stream>>>(rs_row, colv2, X1c, b1 + 8, H1c, n);
        // T = A @ H1, feature halves
        k_spmm8<0><<<sb4, 256, 0, stream>>>(rs_row, colv2, H1a, b1, Ta, n);
        k_spmm8<0><<<sb4, 256, 0, stream>>>(rs_row, colv2, H1c, b1, Tc, n);
        // out = log_softmax(relu(T @ W2 + b2)) — thread per row
        k4_final_split<<<rb, 256, 0, stream>>>(Ta, Tc, W2, b2, out, n);
    } else {
        float* A = (float*)d_ws;
        float* B = A + (size_t)n * DHID;
        unsigned int sb = (unsigned int)(((long long)nnz * DHID + 255) / 256);
        k1_gemm_hw1_f32<<<rb, 256, 0, stream>>>(H, W1, A, n);
        hipMemsetAsync(B, 0, (size_t)n * DHID * sizeof(float), stream);
        k2_scatter16<<<sb, 256, 0, stream>>>(rows, cols, vals, A, nullptr, 0, B, nnz);
        hipMemsetAsync(A, 0, (size_t)n * DHID * sizeof(float), stream);
        k2_scatter16<<<sb, 256, 0, stream>>>(rows, cols, vals, B, b1, 1, A, nnz);
        k4_final_f32<<<rb, 256, 0, stream>>>(A, W2, b2, out, n);
    }
}

// Round 9
// 422.493 us; speedup vs baseline: 1.0538x; 1.0538x over previous
//
#include <hip/hip_runtime.h>

#define DIN   128
#define DHID  16
#define NCLS  40
#define RSH_C 9            // coarse bucket = 512 rows
#define RROWS_C 512
#define BATCH 8192         // edges per k_bucket2 block
#define SORT_CAP 18176     // staged records in k_sortb2 (avg 16384, sigma 128)

__device__ __forceinline__ unsigned short f2bf(float f) {
    unsigned u = __float_as_uint(f);
    unsigned r = (u + 0x7FFFu + ((u >> 16) & 1u)) >> 16;   // RNE
    return (unsigned short)r;
}

// ------------- K1: X1 = H @ W1 -> two bf16 half-tables (n x 8) -------------
__global__ __launch_bounds__(256) void k1_gemm_hw1_split(
    const float* __restrict__ H, const float* __restrict__ W1,
    unsigned short* __restrict__ X1a, unsigned short* __restrict__ X1c, int n)
{
    __shared__ __align__(16) float w[DIN * DHID];
    for (int i = threadIdx.x; i < DIN * DHID; i += 256) w[i] = W1[i];
    __syncthreads();
    int r = blockIdx.x * 256 + threadIdx.x;
    if (r >= n) return;
    const float4* hrow = (const float4*)(H + (size_t)r * DIN);
    float acc[DHID];
#pragma unroll
    for (int j = 0; j < DHID; ++j) acc[j] = 0.f;
#pragma unroll 4
    for (int k4 = 0; k4 < DIN / 4; ++k4) {
        float4 h = hrow[k4];
        float hh[4] = {h.x, h.y, h.z, h.w};
#pragma unroll
        for (int kk = 0; kk < 4; ++kk) {
#pragma unroll
            for (int j4 = 0; j4 < DHID / 4; ++j4) {
                float4 wv = *(const float4*)&w[(4 * k4 + kk) * DHID + 4 * j4];
                acc[4 * j4 + 0] += hh[kk] * wv.x;
                acc[4 * j4 + 1] += hh[kk] * wv.y;
                acc[4 * j4 + 2] += hh[kk] * wv.z;
                acc[4 * j4 + 3] += hh[kk] * wv.w;
            }
        }
    }
    unsigned pk[8];
#pragma unroll
    for (int q = 0; q < 8; ++q)
        pk[q] = (unsigned)f2bf(acc[2 * q]) | ((unsigned)f2bf(acc[2 * q + 1]) << 16);
    *(uint4*)(X1a + (size_t)r * 8) = make_uint4(pk[0], pk[1], pk[2], pk[3]);
    *(uint4*)(X1c + (size_t)r * 8) = make_uint4(pk[4], pk[5], pk[6], pk[7]);
}

// ---------------- coarse histogram (4-way dup LDS counters) ----------------
__global__ __launch_bounds__(256) void k_hist_b(
    const int* __restrict__ rows, unsigned* __restrict__ gcnt, int nnz, int nb)
{
    __shared__ unsigned c4[4][RROWS_C];
    int tid = threadIdx.x;
    for (int i = tid; i < 4 * RROWS_C; i += 256) ((unsigned*)c4)[i] = 0;
    __syncthreads();
    int cp = (tid >> 6) & 3;
    for (int e = blockIdx.x * 256 + tid; e < nnz; e += gridDim.x * 256)
        atomicAdd(&c4[cp][((unsigned)rows[e]) >> RSH_C], 1u);
    __syncthreads();
    for (int b = tid; b < nb; b += 256) {
        unsigned s = c4[0][b] + c4[1][b] + c4[2][b] + c4[3][b];
        if (s) atomicAdd(&gcnt[b], s);
    }
}

// ---------------- single-block scan over nb (<=512) buckets ----------------
__global__ __launch_bounds__(512) void k_scan_all(
    const unsigned* __restrict__ cnt, unsigned* __restrict__ rs_b,
    unsigned* __restrict__ cur_b, int nb, unsigned nnz)
{
    __shared__ unsigned s[512];
    int tid = threadIdx.x;
    unsigned v = (tid < nb) ? cnt[tid] : 0u;
    s[tid] = v; __syncthreads();
    for (int off = 1; off < 512; off <<= 1) {
        unsigned t = (tid >= off) ? s[tid - off] : 0u;
        __syncthreads();
        s[tid] += t;
        __syncthreads();
    }
    if (tid < nb) {
        unsigned e = s[tid] - v;
        rs_b[tid] = e;
        cur_b[tid] = e;
    }
    if (tid == 0) rs_b[nb] = nnz;
}

// ------- bucket placement v3: split colB/rowB arrays, slim LDS -------------
// colB record = col(18b) | q14(14b);  rowB = local row (u16)
__global__ __launch_bounds__(512) void k_bucket2(
    const int* __restrict__ rows, const int* __restrict__ cols,
    const float* __restrict__ vals, unsigned* __restrict__ gcur,
    unsigned* __restrict__ colB, unsigned short* __restrict__ rowB,
    int nnz, int nb)
{
    __shared__ unsigned stC[BATCH];            // 32 KB bucket-sorted records
    __shared__ unsigned short stR[BATCH];      // 16 KB local rows
    __shared__ unsigned short bbk[BATCH];      // 16 KB bucket id per slot
    __shared__ unsigned h2[2][512];            // 4 KB 2-dup histogram
    __shared__ unsigned scn[512];              // 2 KB
    __shared__ unsigned sstart[512];
    __shared__ unsigned pos[512];
    __shared__ unsigned gbase[512];            // total ~76 KB -> 2 blocks/CU
    int tid = threadIdx.x;
    int e0 = blockIdx.x * BATCH;
    int m = nnz - e0; if (m > BATCH) m = BATCH;

    int r_[BATCH / 512]; unsigned rec_[BATCH / 512];
#pragma unroll
    for (int q = 0; q < BATCH / 512; ++q) {
        int i = q * 512 + tid;
        if (i < m) {
            r_[q] = rows[e0 + i];
            float v = vals[e0 + i];
            unsigned qv = (unsigned)(v * 16383.f + 0.5f);
            if (qv > 16383u) qv = 16383u;
            rec_[q] = ((unsigned)cols[e0 + i] & 0x3FFFFu) | (qv << 18);
        }
    }
    for (int i = tid; i < 2 * 512; i += 512) ((unsigned*)h2)[i] = 0;
    __syncthreads();
    int cp = (tid >> 8) & 1;
#pragma unroll
    for (int q = 0; q < BATCH / 512; ++q)
        if (q * 512 + tid < m) atomicAdd(&h2[cp][((unsigned)r_[q]) >> RSH_C], 1u);
    __syncthreads();
    scn[tid] = h2[0][tid] + h2[1][tid];
    __syncthreads();
    for (int off = 1; off < 512; off <<= 1) {
        unsigned t = (tid >= off) ? scn[tid - off] : 0u;
        __syncthreads();
        scn[tid] += t;
        __syncthreads();
    }
    unsigned vcnt = scn[tid] - (tid ? scn[tid - 1] : 0u);
    unsigned excl = scn[tid] - vcnt;
    sstart[tid] = excl;
    pos[tid] = excl;
    gbase[tid] = (tid < nb && vcnt) ? atomicAdd(&gcur[tid], vcnt) : 0u;
    __syncthreads();
#pragma unroll
    for (int q = 0; q < BATCH / 512; ++q) {
        if (q * 512 + tid < m) {
            int b = ((unsigned)r_[q]) >> RSH_C;
            unsigned p = atomicAdd(&pos[b], 1u);
            stC[p] = rec_[q];
            stR[p] = (unsigned short)(r_[q] & (RROWS_C - 1));
            bbk[p] = (unsigned short)b;
        }
    }
    __syncthreads();
    // coalesced flush of both arrays
    for (int i = tid; i < m; i += 512) {
        int b = bbk[i];
        unsigned dst = gbase[b] + (i - sstart[b]);
        colB[dst] = stC[i];
        rowB[dst] = stR[i];
    }
}

// ---- per-bucket counting sort v2: LDS-staged, coalesced colv2 flush -------
__global__ __launch_bounds__(512) void k_sortb2(
    const unsigned* __restrict__ rs_b, const unsigned* __restrict__ colB,
    const unsigned short* __restrict__ rowB,
    unsigned* __restrict__ colv2, unsigned* __restrict__ rs_row,
    int n, int nb, unsigned nnz)
{
    __shared__ unsigned st[SORT_CAP];          // 71 KB sorted staging
    __shared__ unsigned c2[2][RROWS_C];        // 4 KB
    __shared__ unsigned scn[RROWS_C];          // 2 KB
    __shared__ unsigned pos[RROWS_C];          // 2 KB -> ~79 KB total
    int b = blockIdx.x, tid = threadIdx.x;
    unsigned s0 = rs_b[b], s1 = rs_b[b + 1];
    int m = (int)(s1 - s0);
    for (int i = tid; i < 2 * RROWS_C; i += 512) ((unsigned*)c2)[i] = 0;
    __syncthreads();
    int cp = (tid >> 8) & 1;
    for (int i = tid; i < m; i += 512)
        atomicAdd(&c2[cp][rowB[s0 + i]], 1u);
    __syncthreads();
    scn[tid] = c2[0][tid] + c2[1][tid];
    __syncthreads();
    for (int off = 1; off < RROWS_C; off <<= 1) {   // Hillis-Steele inclusive
        unsigned t = (tid >= off) ? scn[tid - off] : 0u;
        __syncthreads();
        scn[tid] += t;
        __syncthreads();
    }
    unsigned excl = tid ? scn[tid - 1] : 0u;
    pos[tid] = excl;
    int row = b * RROWS_C + tid;
    if (row < n) rs_row[row] = s0 + excl;
    if (b == nb - 1 && tid == 0) rs_row[n] = nnz;
    __syncthreads();
    if (m <= SORT_CAP) {
        for (int i = tid; i < m; i += 512) {
            unsigned p = atomicAdd(&pos[rowB[s0 + i]], 1u);
            st[p] = colB[s0 + i];
        }
        __syncthreads();
        for (int i = tid; i < m; i += 512)      // coalesced flush
            colv2[s0 + i] = st[i];
    } else {
        // fallback: direct scattered placement (statistically never taken)
        for (int i = tid; i < m; i += 512) {
            unsigned p = atomicAdd(&pos[rowB[s0 + i]], 1u);
            colv2[s0 + p] = colB[s0 + i];
        }
    }
}

// ---- SpMM over an 8-feature half-table (3.2 MB) ---------------------------
// wave = 32 edge-groups x 2 lanes; lane l loads 4 bf16 (8B) of the row.
template<int RELU>
__global__ __launch_bounds__(256) void k_spmm8(
    const unsigned* __restrict__ rs, const unsigned* __restrict__ colv2,
    const unsigned short* __restrict__ srcb,   // n x 8 bf16
    const float* __restrict__ bias,            // 8 floats for this half
    unsigned short* __restrict__ dstb, int n)  // n x 8 bf16
{
    const float DQ = 1.f / 16383.f;
    int w = blockIdx.x * 4 + (threadIdx.x >> 6);
    if (w >= n) return;
    int lane = threadIdx.x & 63;
    int g = lane >> 1, l = lane & 1;
    unsigned s0 = rs[w], s1 = rs[w + 1];
    float acc0 = 0.f, acc1 = 0.f, acc2 = 0.f, acc3 = 0.f;
    for (unsigned i = s0 + g; i < s1; i += 32) {
        unsigned rec = colv2[i];
        float vv = (float)(rec >> 18) * DQ;
        uint2 d = *((const uint2*)(srcb + (size_t)(rec & 0x3FFFFu) * 8) + l);
        acc0 += __uint_as_float(d.x << 16) * vv;
        acc1 += __uint_as_float(d.x & 0xFFFF0000u) * vv;
        acc2 += __uint_as_float(d.y << 16) * vv;
        acc3 += __uint_as_float(d.y & 0xFFFF0000u) * vv;
    }
#pragma unroll
    for (int off = 2; off < 64; off <<= 1) {
        acc0 += __shfl_xor(acc0, off, 64);
        acc1 += __shfl_xor(acc1, off, 64);
        acc2 += __shfl_xor(acc2, off, 64);
        acc3 += __shfl_xor(acc3, off, 64);
    }
    if (lane < 2) {
        float4 bv = ((const float4*)bias)[l];
        float a0, a1, a2, a3;
        if (RELU) {
            a0 = fmaxf(acc0 + bv.x, 0.f);
            a1 = fmaxf(acc1 + bv.y, 0.f);
            a2 = fmaxf(acc2 + bv.z, 0.f);
            a3 = fmaxf(acc3 + bv.w, 0.f);
        } else {
            a0 = acc0; a1 = acc1; a2 = acc2; a3 = acc3;
        }
        uint2 pk;
        pk.x = (unsigned)f2bf(a0) | ((unsigned)f2bf(a1) << 16);
        pk.y = (unsigned)f2bf(a2) | ((unsigned)f2bf(a3) << 16);
        *((uint2*)(dstb + (size_t)w * 8) + l) = pk;
    }
}

// ----- K4: out = log_softmax(relu([Ta|Tc] @ W2 + b2)), thread per row ------
__global__ __launch_bounds__(256) void k4_final_split(
    const unsigned short* __restrict__ Ta, const unsigned short* __restrict__ Tc,
    const float* __restrict__ W2, const float* __restrict__ b2,
    float* __restrict__ out, int n)
{
    __shared__ __align__(16) float w[DHID * NCLS];
    __shared__ float bb[NCLS];
    for (int i = threadIdx.x; i < DHID * NCLS; i += 256) w[i] = W2[i];
    if (threadIdx.x < NCLS) bb[threadIdx.x] = b2[threadIdx.x];
    __syncthreads();
    int r = blockIdx.x * 256 + threadIdx.x;
    if (r >= n) return;
    uint4 pa = *(const uint4*)(Ta + (size_t)r * 8);
    uint4 pc = *(const uint4*)(Tc + (size_t)r * 8);
    unsigned u[8] = {pa.x, pa.y, pa.z, pa.w, pc.x, pc.y, pc.z, pc.w};
    float t[DHID];
#pragma unroll
    for (int q = 0; q < 8; ++q) {
        t[2 * q]     = __uint_as_float(u[q] << 16);
        t[2 * q + 1] = __uint_as_float(u[q] & 0xFFFF0000u);
    }
    float o[NCLS];
#pragma unroll
    for (int j = 0; j < NCLS; ++j) o[j] = bb[j];
#pragma unroll 4
    for (int k = 0; k < DHID; ++k) {
        float tk = t[k];
#pragma unroll
        for (int j4 = 0; j4 < NCLS / 4; ++j4) {
            float4 wv = *(const float4*)&w[k * NCLS + 4 * j4];
            o[4*j4+0] += tk * wv.x;
            o[4*j4+1] += tk * wv.y;
            o[4*j4+2] += tk * wv.z;
            o[4*j4+3] += tk * wv.w;
        }
    }
    float mx = 0.f;
#pragma unroll
    for (int j = 0; j < NCLS; ++j) {
        o[j] = fmaxf(o[j], 0.f);
        mx = fmaxf(mx, o[j]);
    }
    float s = 0.f;
#pragma unroll
    for (int j = 0; j < NCLS; ++j) s += __expf(o[j] - mx);
    float ls = mx + __logf(s);
    float4* orow = (float4*)(out + (size_t)r * NCLS);
#pragma unroll
    for (int j4 = 0; j4 < NCLS / 4; ++j4)
        orow[j4] = make_float4(o[4*j4+0]-ls, o[4*j4+1]-ls, o[4*j4+2]-ls, o[4*j4+3]-ls);
}

// ---------------- fallback (round-1 scatter path, fp32) ----------------
__global__ __launch_bounds__(256) void k1_gemm_hw1_f32(
    const float* __restrict__ H, const float* __restrict__ W1,
    float* __restrict__ X1, int n)
{
    __shared__ __align__(16) float w[DIN * DHID];
    for (int i = threadIdx.x; i < DIN * DHID; i += 256) w[i] = W1[i];
    __syncthreads();
    int r = blockIdx.x * 256 + threadIdx.x;
    if (r >= n) return;
    const float4* hrow = (const float4*)(H + (size_t)r * DIN);
    float acc[DHID];
#pragma unroll
    for (int j = 0; j < DHID; ++j) acc[j] = 0.f;
    for (int k4 = 0; k4 < DIN / 4; ++k4) {
        float4 h = hrow[k4];
        float hh[4] = {h.x, h.y, h.z, h.w};
#pragma unroll
        for (int kk = 0; kk < 4; ++kk)
#pragma unroll
            for (int j = 0; j < DHID; ++j)
                acc[j] += hh[kk] * w[(4 * k4 + kk) * DHID + j];
    }
    float4* o = (float4*)(X1 + (size_t)r * DHID);
#pragma unroll
    for (int q = 0; q < DHID / 4; ++q)
        o[q] = make_float4(acc[4*q], acc[4*q+1], acc[4*q+2], acc[4*q+3]);
}

__global__ __launch_bounds__(256) void k2_scatter16(
    const int* __restrict__ rows, const int* __restrict__ cols,
    const float* __restrict__ vals, const float* __restrict__ src,
    const float* __restrict__ bias, int do_relu,
    float* __restrict__ dst, int nnz)
{
    unsigned int tid = blockIdx.x * 256u + threadIdx.x;
    int e = (int)(tid >> 4);
    int j = (int)(tid & 15u);
    if (e >= nnz) return;
    int c = cols[e];
    int r = rows[e];
    float x = src[(size_t)c * DHID + j];
    if (do_relu) x = fmaxf(x + bias[j], 0.f);
    atomicAdd(&dst[(size_t)r * DHID + j], x * vals[e]);
}

__global__ __launch_bounds__(256) void k4_final_f32(
    const float* __restrict__ T, const float* __restrict__ W2,
    const float* __restrict__ b2, float* __restrict__ out, int n)
{
    __shared__ __align__(16) float w[DHID * NCLS];
    __shared__ float bb[NCLS];
    for (int i = threadIdx.x; i < DHID * NCLS; i += 256) w[i] = W2[i];
    if (threadIdx.x < NCLS) bb[threadIdx.x] = b2[threadIdx.x];
    __syncthreads();
    int r = blockIdx.x * 256 + threadIdx.x;
    if (r >= n) return;
    float t[DHID];
    const float4* trow = (const float4*)(T + (size_t)r * DHID);
#pragma unroll
    for (int q = 0; q < DHID / 4; ++q) {
        float4 v = trow[q];
        t[4*q+0] = v.x; t[4*q+1] = v.y; t[4*q+2] = v.z; t[4*q+3] = v.w;
    }
    float o[NCLS];
#pragma unroll
    for (int j = 0; j < NCLS; ++j) o[j] = bb[j];
    for (int k = 0; k < DHID; ++k) {
        float tk = t[k];
#pragma unroll
        for (int j = 0; j < NCLS; ++j) o[j] += tk * w[k * NCLS + j];
    }
    float mx = 0.f;
#pragma unroll
    for (int j = 0; j < NCLS; ++j) { o[j] = fmaxf(o[j], 0.f); mx = fmaxf(mx, o[j]); }
    float s = 0.f;
#pragma unroll
    for (int j = 0; j < NCLS; ++j) s += __expf(o[j] - mx);
    float ls = mx + __logf(s);
#pragma unroll
    for (int j = 0; j < NCLS; ++j) out[(size_t)r * NCLS + j] = o[j] - ls;
}

extern "C" void kernel_launch(void* const* d_in, const int* in_sizes, int n_in,
                              void* d_out, int out_size, void* d_ws, size_t ws_size,
                              hipStream_t stream)
{
    const float* H    = (const float*)d_in[0];
    const int*   rows = (const int*)d_in[1];
    const int*   cols = (const int*)d_in[2];
    const float* vals = (const float*)d_in[3];
    const float* W1   = (const float*)d_in[4];
    const float* b1   = (const float*)d_in[5];
    const float* W2   = (const float*)d_in[6];
    const float* b2   = (const float*)d_in[7];
    float* out = (float*)d_out;

    int n   = in_sizes[0] / DIN;              // 200000
    int nnz = in_sizes[1];                    // 6,400,000
    int nb  = (n + RROWS_C - 1) >> RSH_C;     // 391 coarse buckets

    // ---- workspace layout (~65.7 MB) ----
    unsigned* rs_b   = (unsigned*)d_ws;               // nb+1
    unsigned* cur_b  = rs_b + (nb + 1);               // nb
    unsigned* cnt_b  = cur_b + nb;                    // nb
    unsigned* rs_row = cnt_b + nb;                    // n+1
    size_t off = (size_t)((char*)(rs_row + n + 1) - (char*)d_ws);
    off = (off + 63) & ~(size_t)63;
    unsigned* colv2 = (unsigned*)((char*)d_ws + off); // nnz u32 (final CSR)
    off += (size_t)nnz * sizeof(unsigned);
    off = (off + 63) & ~(size_t)63;
    unsigned* colB = (unsigned*)((char*)d_ws + off);  // nnz u32 (bucket stage)
    size_t offB = off;
    off += (size_t)nnz * sizeof(unsigned);
    off = (off + 63) & ~(size_t)63;
    unsigned short* rowB = (unsigned short*)((char*)d_ws + off); // nnz u16
    size_t needed = off + (size_t)nnz * sizeof(unsigned short);
    // feature-split bf16 half-tables overlay colB/rowB (dead after k_sortb2):
    unsigned short* X1a = (unsigned short*)((char*)d_ws + offB); // n*8 bf16
    unsigned short* X1c = X1a + (size_t)n * 8;
    unsigned short* H1a = X1c + (size_t)n * 8;
    unsigned short* H1c = H1a + (size_t)n * 8;
    unsigned short* Ta  = H1c + (size_t)n * 8;
    unsigned short* Tc  = Ta  + (size_t)n * 8;        // 19.2 MB < 38.4 MB

    int rb  = (n + 255) / 256;
    int sb4 = (n + 3) / 4;

    if (nb <= RROWS_C && n <= (1 << 18) && needed <= ws_size) {
        hipMemsetAsync(cnt_b, 0, (size_t)nb * sizeof(unsigned), stream);
        k_hist_b<<<1024, 256, 0, stream>>>(rows, cnt_b, nnz, nb);
        k_scan_all<<<1, 512, 0, stream>>>(cnt_b, rs_b, cur_b, nb, (unsigned)nnz);
        int nbk = (nnz + BATCH - 1) / BATCH;
        k_bucket2<<<nbk, 512, 0, stream>>>(rows, cols, vals, cur_b, colB, rowB, nnz, nb);
        k_sortb2<<<nb, 512, 0, stream>>>(rs_b, colB, rowB, colv2, rs_row, n, nb, (unsigned)nnz);
        // X1 = H @ W1 -> split tables (overlays dead colB/rowB region)
        k1_gemm_hw1_split<<<rb, 256, 0, stream>>>(H, W1, X1a, X1c, n);
        // H1 = relu(A @ X1 + b1), feature halves
        k_spmm8<1><<<sb4, 256, 0, stream>>>(rs_row, colv2, X1a, b1,     H1a, n);
        k_spmm8<1><<<sb4, 256, 0, stream>>>(rs_row, colv2, X1c, b1 + 8, H1c, n);
        // T = A @ H1, feature halves
        k_spmm8<0><<<sb4, 256, 0, stream>>>(rs_row, colv2, H1a, b1, Ta, n);
        k_spmm8<0><<<sb4, 256, 0, stream>>>(rs_row, colv2, H1c, b1, Tc, n);
        // out = log_softmax(relu(T @ W2 + b2))
        k4_final_split<<<rb, 256, 0, stream>>>(Ta, Tc, W2, b2, out, n);
    } else {
        float* A = (float*)d_ws;
        float* B = A + (size_t)n * DHID;
        unsigned int sb = (unsigned int)(((long long)nnz * DHID + 255) / 256);
        k1_gemm_hw1_f32<<<rb, 256, 0, stream>>>(H, W1, A, n);
        hipMemsetAsync(B, 0, (size_t)n * DHID * sizeof(float), stream);
        k2_scatter16<<<sb, 256, 0, stream>>>(rows, cols, vals, A, nullptr, 0, B, nnz);
        hipMemsetAsync(A, 0, (size_t)n * DHID * sizeof(float), stream);
        k2_scatter16<<<sb, 256, 0, stream>>>(rows, cols, vals, B, b1, 1, A, nnz);
        k4_final_f32<<<rb, 256, 0, stream>>>(A, W2, b2, out, n);
    }
}

// Round 10
// 334.580 us; speedup vs baseline: 1.3307x; 1.2628x over previous
//
#include <hip/hip_runtime.h>

#define DIN   128
#define DHID  16
#define NCLS  40
#define RSH_C 9            // coarse bucket = 512 rows
#define RROWS_C 512
#define BATCH 8192         // edges per k_bucket2 block
#define SORT_CAP 17920     // staged records in k_sortb2 (mean 16384, sigma 128)

__device__ __forceinline__ unsigned short f2bf(float f) {
    unsigned u = __float_as_uint(f);
    unsigned r = (u + 0x7FFFu + ((u >> 16) & 1u)) >> 16;   // RNE
    return (unsigned short)r;
}

// inclusive scan across a 64-lane wave
__device__ __forceinline__ unsigned wave_iscan(unsigned x, int lane) {
#pragma unroll
    for (int off = 1; off < 64; off <<= 1) {
        unsigned t = __shfl_up(x, off, 64);
        if (lane >= off) x += t;
    }
    return x;
}

// ---- fused: K1 (X1 = H@W1 -> bf16 n x 16) + coarse histogram --------------
__global__ __launch_bounds__(256) void k1hist(
    const float* __restrict__ H, const float* __restrict__ W1,
    unsigned short* __restrict__ X1,
    const int* __restrict__ rows, unsigned* __restrict__ gcnt,
    int n, int nnz, int rb)
{
    __shared__ unsigned smem[2048];   // 8 KB: W1 (floats) OR 4-dup counters
    int tid = threadIdx.x;
    if ((int)blockIdx.x < rb) {
        float* w = (float*)smem;
        for (int i = tid; i < DIN * DHID; i += 256) w[i] = W1[i];
        __syncthreads();
        int r = blockIdx.x * 256 + tid;
        if (r >= n) return;
        const float4* hrow = (const float4*)(H + (size_t)r * DIN);
        float acc[DHID];
#pragma unroll
        for (int j = 0; j < DHID; ++j) acc[j] = 0.f;
#pragma unroll 4
        for (int k4 = 0; k4 < DIN / 4; ++k4) {
            float4 h = hrow[k4];
            float hh[4] = {h.x, h.y, h.z, h.w};
#pragma unroll
            for (int kk = 0; kk < 4; ++kk) {
#pragma unroll
                for (int j4 = 0; j4 < DHID / 4; ++j4) {
                    float4 wv = *(const float4*)&w[(4 * k4 + kk) * DHID + 4 * j4];
                    acc[4 * j4 + 0] += hh[kk] * wv.x;
                    acc[4 * j4 + 1] += hh[kk] * wv.y;
                    acc[4 * j4 + 2] += hh[kk] * wv.z;
                    acc[4 * j4 + 3] += hh[kk] * wv.w;
                }
            }
        }
        unsigned pk[8];
#pragma unroll
        for (int q = 0; q < 8; ++q)
            pk[q] = (unsigned)f2bf(acc[2 * q]) | ((unsigned)f2bf(acc[2 * q + 1]) << 16);
        uint4* o = (uint4*)(X1 + (size_t)r * DHID);
        o[0] = make_uint4(pk[0], pk[1], pk[2], pk[3]);
        o[1] = make_uint4(pk[4], pk[5], pk[6], pk[7]);
    } else {
        unsigned (*c4)[512] = (unsigned(*)[512])smem;
        for (int i = tid; i < 2048; i += 256) smem[i] = 0;
        __syncthreads();
        int bid = blockIdx.x - rb;
        int cp = (tid >> 6) & 3;
        for (int e = bid * 256 + tid; e < nnz; e += 1024 * 256)
            atomicAdd(&c4[cp][((unsigned)rows[e]) >> RSH_C], 1u);
        __syncthreads();
        for (int b = tid; b < 512; b += 256) {
            unsigned s = c4[0][b] + c4[1][b] + c4[2][b] + c4[3][b];
            if (s) atomicAdd(&gcnt[b], s);
        }
    }
}

// ---------------- single-block scan over nb (<=512) buckets ----------------
__global__ __launch_bounds__(512) void k_scan_all(
    const unsigned* __restrict__ cnt, unsigned* __restrict__ rs_b,
    unsigned* __restrict__ cur_b, int nb, unsigned nnz)
{
    __shared__ unsigned wsum[8], wexcl[8];
    int tid = threadIdx.x;
    int lane = tid & 63, wv = tid >> 6;
    unsigned v = (tid < nb) ? cnt[tid] : 0u;
    unsigned x = wave_iscan(v, lane);
    if (lane == 63) wsum[wv] = x;
    __syncthreads();
    if (tid == 0) {
        unsigned run = 0;
#pragma unroll
        for (int w = 0; w < 8; ++w) { wexcl[w] = run; run += wsum[w]; }
    }
    __syncthreads();
    unsigned excl = x + wexcl[wv] - v;
    if (tid < nb) { rs_b[tid] = excl; cur_b[tid] = excl; }
    if (tid == 0) rs_b[nb] = nnz;
}

// ------- bucket placement: LDS multi-split, 10-bit key, shuffle scan -------
// colB record = col(18b) | q14(14b);  rowB = key = (lr<<1)|(col>=half)
__global__ __launch_bounds__(512) void k_bucket2(
    const int* __restrict__ rows, const int* __restrict__ cols,
    const float* __restrict__ vals, unsigned* __restrict__ gcur,
    unsigned* __restrict__ colB, unsigned short* __restrict__ rowB,
    int nnz, int nb, int half)
{
    __shared__ unsigned stC[BATCH];            // 32 KB
    __shared__ unsigned short stR[BATCH];      // 16 KB
    __shared__ unsigned short bbk[BATCH];      // 16 KB
    __shared__ unsigned h2[2][512];            // 4 KB
    __shared__ unsigned sstart[512];
    __shared__ unsigned pos[512];
    __shared__ unsigned gbase[512];
    __shared__ unsigned wsum[8], wexcl[8];     // ~74 KB total -> 2 blocks/CU
    int tid = threadIdx.x;
    int e0 = blockIdx.x * BATCH;
    int m = nnz - e0; if (m > BATCH) m = BATCH;

    unsigned rec_[BATCH / 512]; unsigned bk_[BATCH / 512];  // bk = bucket<<10 | key
#pragma unroll
    for (int q = 0; q < BATCH / 512; ++q) {
        int i = q * 512 + tid;
        if (i < m) {
            int r = rows[e0 + i];
            int c = cols[e0 + i];
            float v = vals[e0 + i];
            unsigned qv = (unsigned)(v * 16383.f + 0.5f);
            if (qv > 16383u) qv = 16383u;
            rec_[q] = ((unsigned)c & 0x3FFFFu) | (qv << 18);
            unsigned key = (((unsigned)r & (RROWS_C - 1)) << 1) | (c >= half ? 1u : 0u);
            bk_[q] = (((unsigned)r >> RSH_C) << 10) | key;
        }
    }
    for (int i = tid; i < 2 * 512; i += 512) ((unsigned*)h2)[i] = 0;
    __syncthreads();
    int cp = (tid >> 8) & 1;
#pragma unroll
    for (int q = 0; q < BATCH / 512; ++q)
        if (q * 512 + tid < m) atomicAdd(&h2[cp][bk_[q] >> 10], 1u);
    __syncthreads();
    unsigned v = h2[0][tid] + h2[1][tid];
    int lane = tid & 63, wv = tid >> 6;
    unsigned x = wave_iscan(v, lane);
    if (lane == 63) wsum[wv] = x;
    __syncthreads();
    if (tid == 0) {
        unsigned run = 0;
#pragma unroll
        for (int w = 0; w < 8; ++w) { wexcl[w] = run; run += wsum[w]; }
    }
    __syncthreads();
    unsigned excl = x + wexcl[wv] - v;
    sstart[tid] = excl;
    pos[tid] = excl;
    gbase[tid] = (tid < nb && v) ? atomicAdd(&gcur[tid], v) : 0u;
    __syncthreads();
#pragma unroll
    for (int q = 0; q < BATCH / 512; ++q) {
        if (q * 512 + tid < m) {
            int b = bk_[q] >> 10;
            unsigned p = atomicAdd(&pos[b], 1u);
            stC[p] = rec_[q];
            stR[p] = (unsigned short)(bk_[q] & 1023u);
            bbk[p] = (unsigned short)b;
        }
    }
    __syncthreads();
    for (int i = tid; i < m; i += 512) {
        int b = bbk[i];
        unsigned dst = gbase[b] + (i - sstart[b]);
        colB[dst] = stC[i];
        rowB[dst] = stR[i];
    }
}

// ---- per-bucket counting sort by 10-bit key -> (row,srchalf) CSR ----------
__global__ __launch_bounds__(512) void k_sortb2(
    const unsigned* __restrict__ rs_b, const unsigned* __restrict__ colB,
    const unsigned short* __restrict__ rowB,
    unsigned* __restrict__ colv2, unsigned* __restrict__ rs2,
    int n, int nb, unsigned nnz)
{
    __shared__ unsigned st[SORT_CAP];          // 70 KB
    __shared__ unsigned c1[1024];              // 4 KB
    __shared__ unsigned pos[1024];             // 4 KB
    __shared__ unsigned wsum[8], wexcl[8];
    int b = blockIdx.x, tid = threadIdx.x;
    unsigned s0 = rs_b[b], s1 = rs_b[b + 1];
    int m = (int)(s1 - s0);
    for (int i = tid; i < 1024; i += 512) c1[i] = 0;
    __syncthreads();
    for (int i = tid; i < m; i += 512)
        atomicAdd(&c1[rowB[s0 + i]], 1u);
    __syncthreads();
    unsigned c0 = c1[2 * tid], cA = c1[2 * tid + 1];
    unsigned p = c0 + cA;
    int lane = tid & 63, wv = tid >> 6;
    unsigned x = wave_iscan(p, lane);
    if (lane == 63) wsum[wv] = x;
    __syncthreads();
    if (tid == 0) {
        unsigned run = 0;
#pragma unroll
        for (int w = 0; w < 8; ++w) { wexcl[w] = run; run += wsum[w]; }
    }
    __syncthreads();
    unsigned excl = x + wexcl[wv] - p;
    pos[2 * tid] = excl;
    pos[2 * tid + 1] = excl + c0;
    int row = b * RROWS_C + tid;
    if (row < n) {
        rs2[(size_t)row * 2]     = s0 + excl;       // key 2*tid (half 0)
        rs2[(size_t)row * 2 + 1] = s0 + excl + c0;  // key 2*tid+1 (half 1)
    }
    if (b == nb - 1 && tid == 0) rs2[(size_t)n * 2] = nnz;
    __syncthreads();
    if (m <= SORT_CAP) {
        for (int i = tid; i < m; i += 512) {
            unsigned q = atomicAdd(&pos[rowB[s0 + i]], 1u);
            st[q] = colB[s0 + i];
        }
        __syncthreads();
        for (int i = tid; i < m; i += 512)      // coalesced flush
            colv2[s0 + i] = st[i];
    } else {
        for (int i = tid; i < m; i += 512) {    // fallback (never expected)
            unsigned q = atomicAdd(&pos[rowB[s0 + i]], 1u);
            colv2[s0 + q] = colB[s0 + i];
        }
    }
}

// ---- src-split SpMM: full 16-feature gather (32B) from a 3.2 MB window ----
// wave = 2 rows x (16 edge-groups x 2 lanes); lane l loads feats l*8..l*8+7.
// FIN 0: Ppart = sums (f32).  FIN 1: dst = bf16 relu(Ppart+sums+bias).
// FIN 2: Ppart += sums (in place, f32).
template<int PASS, int FIN>
__global__ __launch_bounds__(256) void k_spmm16(
    const unsigned* __restrict__ rs2, const unsigned* __restrict__ colv2,
    const unsigned short* __restrict__ srcb,   // n x 16 bf16
    const float* __restrict__ bias,
    float* __restrict__ Ppart, unsigned short* __restrict__ dstb, int n)
{
    const float DQ = 1.f / 16383.f;
    int row = blockIdx.x * 8 + (threadIdx.x >> 5);
    if (row >= n) return;
    int h32 = threadIdx.x & 31;
    int g = h32 >> 1, l = h32 & 1;
    unsigned s0 = rs2[(size_t)row * 2 + PASS];
    unsigned s1 = rs2[(size_t)row * 2 + PASS + 1];
    float a[8];
#pragma unroll
    for (int j = 0; j < 8; ++j) a[j] = 0.f;
    for (unsigned i = s0 + g; i < s1; i += 16) {
        unsigned rec = colv2[i];
        float vv = (float)(rec >> 18) * DQ;
        uint4 d = *((const uint4*)(srcb + (size_t)(rec & 0x3FFFFu) * DHID) + l);
        a[0] += __uint_as_float(d.x << 16) * vv;
        a[1] += __uint_as_float(d.x & 0xFFFF0000u) * vv;
        a[2] += __uint_as_float(d.y << 16) * vv;
        a[3] += __uint_as_float(d.y & 0xFFFF0000u) * vv;
        a[4] += __uint_as_float(d.z << 16) * vv;
        a[5] += __uint_as_float(d.z & 0xFFFF0000u) * vv;
        a[6] += __uint_as_float(d.w << 16) * vv;
        a[7] += __uint_as_float(d.w & 0xFFFF0000u) * vv;
    }
#pragma unroll
    for (int off = 2; off < 32; off <<= 1) {
#pragma unroll
        for (int j = 0; j < 8; ++j) a[j] += __shfl_xor(a[j], off, 64);
    }
    if (g == 0) {
        float* pp = Ppart + (size_t)row * DHID + l * 8;
        if (FIN == 0) {
            ((float4*)pp)[0] = make_float4(a[0], a[1], a[2], a[3]);
            ((float4*)pp)[1] = make_float4(a[4], a[5], a[6], a[7]);
        } else {
            float4 p0 = ((const float4*)pp)[0], p1 = ((const float4*)pp)[1];
            a[0] += p0.x; a[1] += p0.y; a[2] += p0.z; a[3] += p0.w;
            a[4] += p1.x; a[5] += p1.y; a[6] += p1.z; a[7] += p1.w;
            if (FIN == 1) {
                float4 b0 = ((const float4*)(bias + l * 8))[0];
                float4 b1v = ((const float4*)(bias + l * 8))[1];
                float r0 = fmaxf(a[0] + b0.x, 0.f), r1 = fmaxf(a[1] + b0.y, 0.f);
                float r2 = fmaxf(a[2] + b0.z, 0.f), r3 = fmaxf(a[3] + b0.w, 0.f);
                float r4 = fmaxf(a[4] + b1v.x, 0.f), r5 = fmaxf(a[5] + b1v.y, 0.f);
                float r6 = fmaxf(a[6] + b1v.z, 0.f), r7 = fmaxf(a[7] + b1v.w, 0.f);
                uint4 pk;
                pk.x = (unsigned)f2bf(r0) | ((unsigned)f2bf(r1) << 16);
                pk.y = (unsigned)f2bf(r2) | ((unsigned)f2bf(r3) << 16);
                pk.z = (unsigned)f2bf(r4) | ((unsigned)f2bf(r5) << 16);
                pk.w = (unsigned)f2bf(r6) | ((unsigned)f2bf(r7) << 16);
                *(uint4*)(dstb + (size_t)row * DHID + l * 8) = pk;
            } else {
                ((float4*)pp)[0] = make_float4(a[0], a[1], a[2], a[3]);
                ((float4*)pp)[1] = make_float4(a[4], a[5], a[6], a[7]);
            }
        }
    }
}

// ----- K4: out = log_softmax(relu(T @ W2 + b2)), T = f32 n x 16 ------------
__global__ __launch_bounds__(256) void k4_final(
    const float* __restrict__ T, const float* __restrict__ W2,
    const float* __restrict__ b2, float* __restrict__ out, int n)
{
    __shared__ __align__(16) float w[DHID * NCLS];
    __shared__ float bb[NCLS];
    for (int i = threadIdx.x; i < DHID * NCLS; i += 256) w[i] = W2[i];
    if (threadIdx.x < NCLS) bb[threadIdx.x] = b2[threadIdx.x];
    __syncthreads();
    int r = blockIdx.x * 256 + threadIdx.x;
    if (r >= n) return;
    float t[DHID];
    const float4* trow = (const float4*)(T + (size_t)r * DHID);
#pragma unroll
    for (int q = 0; q < DHID / 4; ++q) {
        float4 v = trow[q];
        t[4*q+0] = v.x; t[4*q+1] = v.y; t[4*q+2] = v.z; t[4*q+3] = v.w;
    }
    float o[NCLS];
#pragma unroll
    for (int j = 0; j < NCLS; ++j) o[j] = bb[j];
#pragma unroll 4
    for (int k = 0; k < DHID; ++k) {
        float tk = t[k];
#pragma unroll
        for (int j4 = 0; j4 < NCLS / 4; ++j4) {
            float4 wv = *(const float4*)&w[k * NCLS + 4 * j4];
            o[4*j4+0] += tk * wv.x;
            o[4*j4+1] += tk * wv.y;
            o[4*j4+2] += tk * wv.z;
            o[4*j4+3] += tk * wv.w;
        }
    }
    float mx = 0.f;
#pragma unroll
    for (int j = 0; j < NCLS; ++j) {
        o[j] = fmaxf(o[j], 0.f);
        mx = fmaxf(mx, o[j]);
    }
    float s = 0.f;
#pragma unroll
    for (int j = 0; j < NCLS; ++j) s += __expf(o[j] - mx);
    float ls = mx + __logf(s);
    float4* orow = (float4*)(out + (size_t)r * NCLS);
#pragma unroll
    for (int j4 = 0; j4 < NCLS / 4; ++j4)
        orow[j4] = make_float4(o[4*j4+0]-ls, o[4*j4+1]-ls, o[4*j4+2]-ls, o[4*j4+3]-ls);
}

// ---------------- fallback (round-1 scatter path, fp32) ----------------
__global__ __launch_bounds__(256) void k1_gemm_hw1_f32(
    const float* __restrict__ H, const float* __restrict__ W1,
    float* __restrict__ X1, int n)
{
    __shared__ __align__(16) float w[DIN * DHID];
    for (int i = threadIdx.x; i < DIN * DHID; i += 256) w[i] = W1[i];
    __syncthreads();
    int r = blockIdx.x * 256 + threadIdx.x;
    if (r >= n) return;
    const float4* hrow = (const float4*)(H + (size_t)r * DIN);
    float acc[DHID];
#pragma unroll
    for (int j = 0; j < DHID; ++j) acc[j] = 0.f;
    for (int k4 = 0; k4 < DIN / 4; ++k4) {
        float4 h = hrow[k4];
        float hh[4] = {h.x, h.y, h.z, h.w};
#pragma unroll
        for (int kk = 0; kk < 4; ++kk)
#pragma unroll
            for (int j = 0; j < DHID; ++j)
                acc[j] += hh[kk] * w[(4 * k4 + kk) * DHID + j];
    }
    float4* o = (float4*)(X1 + (size_t)r * DHID);
#pragma unroll
    for (int q = 0; q < DHID / 4; ++q)
        o[q] = make_float4(acc[4*q], acc[4*q+1], acc[4*q+2], acc[4*q+3]);
}

__global__ __launch_bounds__(256) void k2_scatter16(
    const int* __restrict__ rows, const int* __restrict__ cols,
    const float* __restrict__ vals, const float* __restrict__ src,
    const float* __restrict__ bias, int do_relu,
    float* __restrict__ dst, int nnz)
{
    unsigned int tid = blockIdx.x * 256u + threadIdx.x;
    int e = (int)(tid >> 4);
    int j = (int)(tid & 15u);
    if (e >= nnz) return;
    int c = cols[e];
    int r = rows[e];
    float x = src[(size_t)c * DHID + j];
    if (do_relu) x = fmaxf(x + bias[j], 0.f);
    atomicAdd(&dst[(size_t)r * DHID + j], x * vals[e]);
}

extern "C" void kernel_launch(void* const* d_in, const int* in_sizes, int n_in,
                              void* d_out, int out_size, void* d_ws, size_t ws_size,
                              hipStream_t stream)
{
    const float* H    = (const float*)d_in[0];
    const int*   rows = (const int*)d_in[1];
    const int*   cols = (const int*)d_in[2];
    const float* vals = (const float*)d_in[3];
    const float* W1   = (const float*)d_in[4];
    const float* b1   = (const float*)d_in[5];
    const float* W2   = (const float*)d_in[6];
    const float* b2   = (const float*)d_in[7];
    float* out = (float*)d_out;

    int n   = in_sizes[0] / DIN;              // 200000
    int nnz = in_sizes[1];                    // 6,400,000
    int nb  = (n + RROWS_C - 1) >> RSH_C;     // 391 coarse buckets
    int half = n >> 1;

    // ---- workspace layout (~72.1 MB; R4 proved ws >= 77.65 MB) ----
    unsigned* rs_b   = (unsigned*)d_ws;               // nb+1
    unsigned* cur_b  = rs_b + (nb + 1);               // nb
    unsigned* cnt_b  = cur_b + nb;                    // nb
    unsigned* rs2    = cnt_b + nb;                    // 2n+1
    size_t off = (size_t)((char*)(rs2 + 2 * (size_t)n + 1) - (char*)d_ws);
    off = (off + 63) & ~(size_t)63;
    unsigned* colv2 = (unsigned*)((char*)d_ws + off); // nnz u32 (final CSR)
    off += (size_t)nnz * sizeof(unsigned);
    off = (off + 63) & ~(size_t)63;
    size_t offB = off;
    unsigned* colB = (unsigned*)((char*)d_ws + off);  // nnz u32 (bucket stage)
    off += (size_t)nnz * sizeof(unsigned);
    off = (off + 63) & ~(size_t)63;
    unsigned short* rowB = (unsigned short*)((char*)d_ws + off); // nnz u16
    off += (size_t)nnz * sizeof(unsigned short);
    off = (off + 63) & ~(size_t)63;
    unsigned short* X1 = (unsigned short*)((char*)d_ws + off);   // n*16 bf16 (dedicated)
    size_t needed = off + (size_t)n * DHID * sizeof(unsigned short);
    // overlays on colB (dead after k_sortb2):
    unsigned short* H1 = (unsigned short*)((char*)d_ws + offB);            // n*16 bf16
    float* Ppart = (float*)((char*)d_ws + offB + (size_t)n * DHID * 2);    // n*16 f32

    int rb  = (n + 255) / 256;
    int sg  = (n + 7) / 8;

    if (nb <= RROWS_C && n <= (1 << 18) && needed <= ws_size) {
        hipMemsetAsync(cnt_b, 0, (size_t)nb * sizeof(unsigned), stream);
        // fused X1-GEMM + coarse histogram
        k1hist<<<rb + 1024, 256, 0, stream>>>(H, W1, X1, rows, cnt_b, n, nnz, rb);
        k_scan_all<<<1, 512, 0, stream>>>(cnt_b, rs_b, cur_b, nb, (unsigned)nnz);
        int nbk = (nnz + BATCH - 1) / BATCH;
        k_bucket2<<<nbk, 512, 0, stream>>>(rows, cols, vals, cur_b, colB, rowB, nnz, nb, half);
        k_sortb2<<<nb, 512, 0, stream>>>(rs_b, colB, rowB, colv2, rs2, n, nb, (unsigned)nnz);
        // layer 1: H1 = relu(A @ X1 + b1), src-split two passes
        k_spmm16<0, 0><<<sg, 256, 0, stream>>>(rs2, colv2, X1, nullptr, Ppart, nullptr, n);
        k_spmm16<1, 1><<<sg, 256, 0, stream>>>(rs2, colv2, X1, b1, Ppart, H1, n);
        // layer 2: T = A @ H1 (f32, finalized in Ppart)
        k_spmm16<0, 0><<<sg, 256, 0, stream>>>(rs2, colv2, H1, nullptr, Ppart, nullptr, n);
        k_spmm16<1, 2><<<sg, 256, 0, stream>>>(rs2, colv2, H1, nullptr, Ppart, nullptr, n);
        // out = log_softmax(relu(T @ W2 + b2))
        k4_final<<<rb, 256, 0, stream>>>(Ppart, W2, b2, out, n);
    } else {
        // fallback: round-1 atomic scatter path (needs 25.6 MB ws)
        float* A = (float*)d_ws;
        float* B = A + (size_t)n * DHID;
        unsigned int sb = (unsigned int)(((long long)nnz * DHID + 255) / 256);
        k1_gemm_hw1_f32<<<rb, 256, 0, stream>>>(H, W1, A, n);
        hipMemsetAsync(B, 0, (size_t)n * DHID * sizeof(float), stream);
        k2_scatter16<<<sb, 256, 0, stream>>>(rows, cols, vals, A, nullptr, 0, B, nnz);
        hipMemsetAsync(A, 0, (size_t)n * DHID * sizeof(float), stream);
        k2_scatter16<<<sb, 256, 0, stream>>>(rows, cols, vals, B, b1, 1, A, nnz);
        k4_final<<<rb, 256, 0, stream>>>(A, W2, b2, out, n);
    }
}